// Round 9
// baseline (28.698 us; speedup 1.0000x reference)
//
#include <hip/hip_runtime.h>
#include <hip/hip_bf16.h>

constexpr int HIDDEN = 256;
constexpr int BAG    = 32;
constexpr int FEAT   = 41025;   // FEATURE_COUNT + 1 (includes zero pad row)
constexpr int NJ     = 64;      // P columns: [0:32]=us-proj, [32:64]=them-proj
constexpr int NTILES = (FEAT + 63) / 64;   // 642 tiles of 64 rows
constexpr int GRID0  = 256;     // persistent-ish: 1 block/CU, 2-3 tiles each

using bf16x8 = __attribute__((ext_vector_type(8))) short;
using f32x4  = __attribute__((ext_vector_type(4))) float;

typedef const __attribute__((address_space(1))) unsigned int* gas_u32;
typedef __attribute__((address_space(3))) unsigned int*       las_u32;

__device__ inline void load_lds16(const float* g, float* l) {
    // async global->LDS, 16B/lane; LDS dest = uniform base + lane*16
    __builtin_amdgcn_global_load_lds((gas_u32)(const void*)g,
                                     (las_u32)(void*)l, 16, 0, 0);
}

__device__ inline short f2bf(float f) {            // fp32 -> bf16 RNE
    __hip_bfloat16 h = __float2bfloat16(f);        // pairs fuse to v_cvt_pk_bf16_f32
    return __builtin_bit_cast(short, h);
}
__device__ inline bf16x8 pack8(float4 a, float4 b) {
    bf16x8 r;
    r[0]=f2bf(a.x); r[1]=f2bf(a.y); r[2]=f2bf(a.z); r[3]=f2bf(a.w);
    r[4]=f2bf(b.x); r[5]=f2bf(b.y); r[6]=f2bf(b.z); r[7]=f2bf(b.w);
    return r;
}

// ---------- k0: P = emb @ W2d via bf16 MFMA; fp32 LDS staged by global_load_lds.
// LDS layout (A and B alike): row-major [64 rows][256 f32], quad(16B)-swizzled:
//   LDS[row][quad q] = global[row][quad q ^ (row&7)]   (stage: per-lane global src)
//   reads use the same XOR -> 64 lanes hit all 8 bank-quads x8 = conflict-free.
__global__ __launch_bounds__(256) void k0_project_mfma(
    const float* __restrict__ emb,
    const float* __restrict__ fc1_w,
    float*       __restrict__ P)
{
    __shared__ float abuf[2][64 * 256];   // 2 x 64 KB (B staged into abuf[1] first)

    const int tid  = threadIdx.x;
    const int lane = tid & 63, wave = tid >> 6;
    const int g = lane >> 4, ml = lane & 15;
    const int mw = wave * 16;             // wave's 16 A-rows

    // ---- stage B (fp32) into abuf[1]: row j holds W2d col j = fc1_w[j&31][(j>>5)*256+k]
#pragma unroll
    for (int i = 0; i < 16; ++i) {
        const int j = mw + i;
        const float* gp = fc1_w + (size_t)(j & 31) * 512 + ((j >> 5) << 8)
                                + ((lane ^ (j & 7)) << 2);
        load_lds16(gp, &abuf[1][j * 256]);
    }
    // ---- stage A(tile0) into abuf[0]
    int t = blockIdx.x;
    {
#pragma unroll
        for (int i = 0; i < 16; ++i) {
            const int r = mw + i;
            int grow = t * 64 + r; if (grow >= FEAT) grow = FEAT - 1;
            const float* gp = emb + (size_t)grow * 256 + ((lane ^ (r & 7)) << 2);
            load_lds16(gp, &abuf[0][r * 256]);
        }
    }
    __syncthreads();                      // drains all global_load_lds

    // ---- read B fragments to registers (tile-invariant): breg[nt][kt], 128 VGPR
    bf16x8 breg[4][8];
#pragma unroll
    for (int nt = 0; nt < 4; ++nt) {
        const int rb = nt * 16 + ml, sw = rb & 7;
        const float* rp = &abuf[1][rb * 256];
#pragma unroll
        for (int kt = 0; kt < 8; ++kt) {
            const int q0 = kt * 8 + g * 2;
            const float4 x0 = *reinterpret_cast<const float4*>(rp + ((q0 ^ sw) << 2));
            const float4 x1 = *reinterpret_cast<const float4*>(rp + (((q0 + 1) ^ sw) << 2));
            breg[nt][kt] = pack8(x0, x1);
        }
    }
    __syncthreads();                      // all waves done reading abuf[1]

    // ---- tile loop: stage(next) async under MFMA(cur); 1 barrier/tile
    int cur = 0;
    while (true) {
        const int nxt = t + GRID0;
        if (nxt < NTILES) {
            float* dst = abuf[cur ^ 1];
#pragma unroll
            for (int i = 0; i < 16; ++i) {
                const int r = mw + i;
                int grow = nxt * 64 + r; if (grow >= FEAT) grow = FEAT - 1;
                const float* gp = emb + (size_t)grow * 256 + ((lane ^ (r & 7)) << 2);
                load_lds16(gp, &dst[r * 256]);
            }
        }

        f32x4 acc[4] = {{0.f,0.f,0.f,0.f},{0.f,0.f,0.f,0.f},
                        {0.f,0.f,0.f,0.f},{0.f,0.f,0.f,0.f}};
        {
            const int ra = mw + ml, sw = ra & 7;
            const float* rp = &abuf[cur][ra * 256];
#pragma unroll
            for (int kt = 0; kt < 8; ++kt) {
                const int q0 = kt * 8 + g * 2;
                const float4 x0 = *reinterpret_cast<const float4*>(rp + ((q0 ^ sw) << 2));
                const float4 x1 = *reinterpret_cast<const float4*>(rp + (((q0 + 1) ^ sw) << 2));
                const bf16x8 af = pack8(x0, x1);
#pragma unroll
                for (int nt = 0; nt < 4; ++nt)
                    acc[nt] = __builtin_amdgcn_mfma_f32_16x16x32_bf16(af, breg[nt][kt],
                                                                      acc[nt], 0, 0, 0);
            }
        }
        // D layout: row = g*4 + r, col = ml
#pragma unroll
        for (int nt = 0; nt < 4; ++nt) {
#pragma unroll
            for (int r = 0; r < 4; ++r) {
                const int f = t * 64 + mw + g * 4 + r;
                if (f < FEAT)
                    P[(size_t)f * NJ + nt * 16 + ml] = acc[nt][r];
            }
        }

        if (nxt >= NTILES) break;
        __syncthreads();                  // next tile staged + cur free for overwrite
        cur ^= 1; t = nxt;
    }
}

// ---------- k1: gather P rows (128 B each) + fused MLP. One wave per batch row.
__global__ __launch_bounds__(256) void k1_gather_mlp(
    const int*   __restrict__ us,
    const int*   __restrict__ them,
    const float* __restrict__ P,
    const float* __restrict__ b1,
    const float* __restrict__ w2, const float* __restrict__ b2,
    const float* __restrict__ w3, const float* __restrict__ b3,
    float*       __restrict__ out)
{
    __shared__ float w2_lds[32][33];
    __shared__ float y1_lds[4][32];

    const int tid  = threadIdx.x;
    const int wave = tid >> 6;
    const int lane = tid & 63;

    for (int k = tid; k < 32 * 32; k += 256)
        w2_lds[k >> 5][k & 31] = w2[k];
    __syncthreads();

    const int row = blockIdx.x * 4 + wave;
    int idx;
    {
        const int* up = us   + (size_t)row * BAG;
        const int* tp = them + (size_t)row * BAG;
        idx = (lane < BAG) ? up[lane] : tp[lane - BAG];
    }

    float acc = 0.f;
    const int srcbase = lane & 32;
#pragma unroll
    for (int i = 0; i < BAG; ++i) {
        const int f = __shfl(idx, srcbase + i);
        acc += P[(size_t)f * NJ + lane];
    }
    acc += __shfl_xor(acc, 32);

    if (lane < 32)
        y1_lds[wave][lane] = fminf(fmaxf(acc + b1[lane], 0.f), 1.f);
    __syncthreads();

    float r3 = 0.f;
    if (lane < 32) {
        float s = b2[lane];
#pragma unroll
        for (int k = 0; k < 32; ++k) s += y1_lds[wave][k] * w2_lds[lane][k];
        r3 = fminf(fmaxf(s, 0.f), 1.f) * w3[lane];
    }
    r3 += __shfl_xor(r3, 16); r3 += __shfl_xor(r3, 8); r3 += __shfl_xor(r3, 4);
    r3 += __shfl_xor(r3, 2);  r3 += __shfl_xor(r3, 1);
    if (lane == 0) out[row] = tanhf(r3 + b3[0]);
}

// ---------- fallback: R0 monolithic kernel (if ws too small) ----------
__global__ __launch_bounds__(256) void nnue_fused(
    const int*   __restrict__ us,
    const int*   __restrict__ them,
    const float* __restrict__ emb,
    const float* __restrict__ w1, const float* __restrict__ b1,
    const float* __restrict__ w2, const float* __restrict__ b2,
    const float* __restrict__ w3, const float* __restrict__ b3,
    float*       __restrict__ out)
{
    __shared__ float x_lds[4][2 * HIDDEN];
    __shared__ float y1_lds[4][32];
    __shared__ float y2_lds[4][32];

    const int tid  = threadIdx.x;
    const int wave = tid >> 6;
    const int lane = tid & 63;
    const int row  = blockIdx.x * 4 + wave;

    int myidx;
    {
        const int* up = us   + (size_t)row * BAG;
        const int* tp = them + (size_t)row * BAG;
        myidx = (lane < BAG) ? up[lane] : tp[lane - BAG];
    }
    const float4* emb4 = reinterpret_cast<const float4*>(emb);
    float4 accU = make_float4(0.f, 0.f, 0.f, 0.f);
    float4 accT = make_float4(0.f, 0.f, 0.f, 0.f);
#pragma unroll
    for (int i = 0; i < BAG; ++i) {
        const int iu = __shfl(myidx, i);
        const int it = __shfl(myidx, BAG + i);
        const float4 vu = emb4[(size_t)iu * (HIDDEN / 4) + lane];
        const float4 vt = emb4[(size_t)it * (HIDDEN / 4) + lane];
        accU.x += vu.x; accU.y += vu.y; accU.z += vu.z; accU.w += vu.w;
        accT.x += vt.x; accT.y += vt.y; accT.z += vt.z; accT.w += vt.w;
    }
    {
        float4* xv = reinterpret_cast<float4*>(&x_lds[wave][0]);
        xv[lane]      = accU;
        xv[64 + lane] = accT;
    }
    __syncthreads();
    {
        const int r    = tid >> 6;
        const int sub  = tid & 63;
        const int j    = sub >> 1;
        const int half = sub & 1;
        const float4* xr = reinterpret_cast<const float4*>(&x_lds[r][0]) + half * 64;
        const float4* wr = reinterpret_cast<const float4*>(w1 + (size_t)j * (2 * HIDDEN)) + half * 64;
        float s = 0.f;
#pragma unroll 8
        for (int k = 0; k < 64; ++k) {
            const float4 xk = xr[k];
            const float4 wk = wr[k];
            s += xk.x * wk.x + xk.y * wk.y + xk.z * wk.z + xk.w * wk.w;
        }
        s += __shfl_xor(s, 1);
        if (half == 0) { s += b1[j]; y1_lds[r][j] = fminf(fmaxf(s, 0.f), 1.f); }
    }
    __syncthreads();
    if (tid < 4 * 32) {
        const int r = tid >> 5;
        const int j = tid & 31;
        const float* wr = w2 + j * 32;
        float s = b2[j];
#pragma unroll
        for (int k = 0; k < 32; ++k) s += y1_lds[r][k] * wr[k];
        y2_lds[r][j] = fminf(fmaxf(s, 0.f), 1.f);
    }
    __syncthreads();
    if (tid < 4) {
        const int r = tid;
        float s = b3[0];
#pragma unroll
        for (int k = 0; k < 32; ++k) s += y2_lds[r][k] * w3[k];
        out[blockIdx.x * 4 + r] = tanhf(s);
    }
}

extern "C" void kernel_launch(void* const* d_in, const int* in_sizes, int n_in,
                              void* d_out, int out_size, void* d_ws, size_t ws_size,
                              hipStream_t stream) {
    const int*   us   = (const int*)  d_in[0];
    const int*   them = (const int*)  d_in[1];
    const float* emb  = (const float*)d_in[2];
    const float* w1   = (const float*)d_in[3];
    const float* b1   = (const float*)d_in[4];
    const float* w2   = (const float*)d_in[5];
    const float* b2   = (const float*)d_in[6];
    const float* w3   = (const float*)d_in[7];
    const float* b3   = (const float*)d_in[8];
    float* out = (float*)d_out;

    const int batch = in_sizes[0] / BAG;                       // 8192
    const size_t p_bytes = (size_t)FEAT * NJ * sizeof(float);  // 10.5 MB

    if (ws_size >= p_bytes) {
        float* P = (float*)d_ws;
        k0_project_mfma<<<GRID0, 256, 0, stream>>>(emb, w1, P);
        k1_gather_mlp<<<batch / 4, 256, 0, stream>>>(us, them, P,
                                                     b1, w2, b2, w3, b3, out);
    } else {
        nnue_fused<<<(batch + 3) / 4, 256, 0, stream>>>(us, them, emb,
                                                        w1, b1, w2, b2, w3, b3, out);
    }
}